// Round 1
// baseline (24342.204 us; speedup 1.0000x reference)
//
#include <hip/hip_runtime.h>
#include <hip/hip_bf16.h>
#include <math.h>

// Problem constants (SimpleLM): L=6, B=4, T=1024, V=32000, E=768, H=12, D=64
#define L_LAYERS 6
#define BB 4
#define TT 1024
#define VV 32000
#define EE 768
#define HH 12
#define DD 64
#define BT (BB * TT)          // 4096 rows of activations

// ---------------------------------------------------------------------------
// Embedding: x[b,t,e] = tok_emb[idx[b,t], e] + pos_emb[t, e]
// ---------------------------------------------------------------------------
__global__ __launch_bounds__(256) void embed_kernel(
    const int* __restrict__ idx, const float* __restrict__ tok_emb,
    const float* __restrict__ pos_emb, float* __restrict__ x)
{
    int i = blockIdx.x * 256 + threadIdx.x;          // < BT*EE
    int e  = i % EE;
    int bt = i / EE;
    int t  = bt % TT;
    int tok = idx[bt];
    x[i] = tok_emb[(size_t)tok * EE + e] + pos_emb[(size_t)t * EE + e];
}

// ---------------------------------------------------------------------------
// LayerNorm over last dim (E=768). One block (256 thr) per row; 3 elems/thr.
// ---------------------------------------------------------------------------
__global__ __launch_bounds__(256) void ln_kernel(
    const float* __restrict__ X, const float* __restrict__ w,
    const float* __restrict__ b, float* __restrict__ Y)
{
    const int tid = threadIdx.x;
    const size_t row = blockIdx.x;
    const float* x = X + row * EE;

    float v0 = x[tid], v1 = x[tid + 256], v2 = x[tid + 512];

    __shared__ float red[256];
    // mean
    red[tid] = v0 + v1 + v2;
    __syncthreads();
    for (int off = 128; off > 0; off >>= 1) {
        if (tid < off) red[tid] += red[tid + off];
        __syncthreads();
    }
    float mean = red[0] * (1.0f / EE);
    __syncthreads();
    // variance
    float d0 = v0 - mean, d1 = v1 - mean, d2 = v2 - mean;
    red[tid] = d0 * d0 + d1 * d1 + d2 * d2;
    __syncthreads();
    for (int off = 128; off > 0; off >>= 1) {
        if (tid < off) red[tid] += red[tid + off];
        __syncthreads();
    }
    float rstd = rsqrtf(red[0] * (1.0f / EE) + 1e-5f);

    float* y = Y + row * EE;
    y[tid]       = d0 * rstd * w[tid]       + b[tid];
    y[tid + 256] = d1 * rstd * w[tid + 256] + b[tid + 256];
    y[tid + 512] = d2 * rstd * w[tid + 512] + b[tid + 512];
}

// ---------------------------------------------------------------------------
// Tiled f32 GEMM: C[M,N] = A[M,K] @ B[K,N] (+bias) (+res) (+relu)
// 64x64 tile, BK=16, 256 threads, each thread 4x4. All dims multiples of 64/16.
// ---------------------------------------------------------------------------
template<int RELU, int RES>
__global__ __launch_bounds__(256) void gemm_f32(
    const float* __restrict__ A, const float* __restrict__ B,
    const float* __restrict__ bias, const float* __restrict__ res,
    float* __restrict__ C, int M, int N, int K)
{
    __shared__ float As[16][64];
    __shared__ float Bs[16][64];

    const int tid = threadIdx.x;
    const int m0 = blockIdx.y * 64;
    const int n0 = blockIdx.x * 64;
    const int tx = tid & 15;     // n dir (4 cols each)
    const int ty = tid >> 4;     // m dir (4 rows each)

    float acc[4][4] = {};

    for (int k0 = 0; k0 < K; k0 += 16) {
        #pragma unroll
        for (int i = 0; i < 4; i++) {
            int idx = tid + i * 256;             // 0..1023
            int m = idx >> 4, k = idx & 15;      // A tile 64x16, coalesced over k
            As[k][m] = A[(size_t)(m0 + m) * K + (k0 + k)];
        }
        #pragma unroll
        for (int i = 0; i < 4; i++) {
            int idx = tid + i * 256;
            int n = idx & 63, k = idx >> 6;      // B tile 16x64, coalesced over n
            Bs[k][n] = B[(size_t)(k0 + k) * N + (n0 + n)];
        }
        __syncthreads();
        #pragma unroll
        for (int k = 0; k < 16; k++) {
            float a[4], bv[4];
            #pragma unroll
            for (int i = 0; i < 4; i++) a[i]  = As[k][ty * 4 + i];
            #pragma unroll
            for (int j = 0; j < 4; j++) bv[j] = Bs[k][tx * 4 + j];
            #pragma unroll
            for (int i = 0; i < 4; i++)
                #pragma unroll
                for (int j = 0; j < 4; j++)
                    acc[i][j] += a[i] * bv[j];
        }
        __syncthreads();
    }

    #pragma unroll
    for (int i = 0; i < 4; i++) {
        int m = m0 + ty * 4 + i;
        #pragma unroll
        for (int j = 0; j < 4; j++) {
            int n = n0 + tx * 4 + j;
            float v = acc[i][j];
            if (bias) v += bias[n];
            if (RES)  v += res[(size_t)m * N + n];
            if (RELU) v = fmaxf(v, 0.0f);
            C[(size_t)m * N + n] = v;
        }
    }
}

// ---------------------------------------------------------------------------
// Causal attention, one block per (b, h, q). Layouts are [B, T, H, D].
// Scores for k<=q in LDS, block softmax, partitioned PV (4 partials x 64 dims).
// ---------------------------------------------------------------------------
__global__ __launch_bounds__(256) void attn_kernel(
    const float* __restrict__ Q, const float* __restrict__ K,
    const float* __restrict__ V, float* __restrict__ O)
{
    const int tid = threadIdx.x;
    const int qt = blockIdx.x;
    const int h  = blockIdx.y;
    const int b  = blockIdx.z;
    const int nk = qt + 1;

    __shared__ float sQ[DD];
    __shared__ float sS[TT];
    __shared__ float red[256];
    __shared__ float sRed[4][DD];

    const float* qrow = Q + ((size_t)(b * TT + qt) * HH + h) * DD;
    if (tid < DD) sQ[tid] = qrow[tid];
    __syncthreads();

    // scores
    for (int kt = tid; kt < nk; kt += 256) {
        const float* krow = K + ((size_t)(b * TT + kt) * HH + h) * DD;
        float acc = 0.0f;
        #pragma unroll
        for (int d = 0; d < DD; d++) acc += sQ[d] * krow[d];
        sS[kt] = acc * 0.125f;   // D^-0.5 = 1/8
    }
    __syncthreads();

    // max
    float m = -INFINITY;
    for (int i = tid; i < nk; i += 256) m = fmaxf(m, sS[i]);
    red[tid] = m;
    __syncthreads();
    for (int off = 128; off > 0; off >>= 1) {
        if (tid < off) red[tid] = fmaxf(red[tid], red[tid + off]);
        __syncthreads();
    }
    m = red[0];
    __syncthreads();

    // exp + sum
    float s = 0.0f;
    for (int i = tid; i < nk; i += 256) {
        float e = __expf(sS[i] - m);
        sS[i] = e;
        s += e;
    }
    red[tid] = s;
    __syncthreads();
    for (int off = 128; off > 0; off >>= 1) {
        if (tid < off) red[tid] += red[tid + off];
        __syncthreads();
    }
    const float inv_total = 1.0f / red[0];
    __syncthreads();

    // PV: thread t handles dim d = t&63, k-partition part = t>>6 (stride 4)
    const int d = tid & 63;
    const int part = tid >> 6;
    float acc = 0.0f;
    for (int kt = part; kt < nk; kt += 4)
        acc += sS[kt] * V[((size_t)(b * TT + kt) * HH + h) * DD + d];
    sRed[part][d] = acc;
    __syncthreads();
    if (part == 0) {
        float r = sRed[0][d] + sRed[1][d] + sRed[2][d] + sRed[3][d];
        O[((size_t)(b * TT + qt) * HH + h) * DD + d] = r * inv_total;
    }
}

// ---------------------------------------------------------------------------
// Host-side launch
// ---------------------------------------------------------------------------
extern "C" void kernel_launch(void* const* d_in, const int* in_sizes, int n_in,
                              void* d_out, int out_size, void* d_ws, size_t ws_size,
                              hipStream_t stream)
{
    (void)in_sizes; (void)n_in; (void)out_size; (void)ws_size;

    const int*   idx     = (const int*)  d_in[0];
    const float* tok_emb = (const float*)d_in[1];
    const float* pos_emb = (const float*)d_in[2];
    const float* ln1_w   = (const float*)d_in[3];
    const float* ln1_b   = (const float*)d_in[4];
    const float* wq      = (const float*)d_in[5];
    const float* wk      = (const float*)d_in[6];
    const float* wv      = (const float*)d_in[7];
    const float* wo      = (const float*)d_in[8];
    const float* bo      = (const float*)d_in[9];
    const float* ln2_w   = (const float*)d_in[10];
    const float* ln2_b   = (const float*)d_in[11];
    const float* w1      = (const float*)d_in[12];
    const float* b1      = (const float*)d_in[13];
    const float* w2      = (const float*)d_in[14];
    const float* b2      = (const float*)d_in[15];
    const float* lnf_w   = (const float*)d_in[16];
    const float* lnf_b   = (const float*)d_in[17];
    const float* head_w  = (const float*)d_in[18];
    const float* head_b  = (const float*)d_in[19];
    float* out = (float*)d_out;

    // workspace carve (all f32): 6 buffers, ~114 MB total
    const size_t S = (size_t)BT * EE;                // 3,145,728
    float* x   = (float*)d_ws;
    float* h   = x + S;      // LN1 out, then attention out
    float* q   = h + S;      // Q, then LN2 out
    float* k   = q + S;
    float* v   = k + S;
    float* ffh = v + S;      // [BT, 4E]

    embed_kernel<<<BT * EE / 256, 256, 0, stream>>>(idx, tok_emb, pos_emb, x);

    const dim3 gE (EE / 64,     BT / 64);   // N=768
    const dim3 gF (4*EE / 64,   BT / 64);   // N=3072
    const dim3 gV (VV / 64,     BT / 64);   // N=32000

    for (int l = 0; l < L_LAYERS; l++) {
        const size_t oE  = (size_t)l * EE;
        const size_t oEE = (size_t)l * EE * EE;
        const size_t oEF = (size_t)l * EE * 4 * EE;

        // h = LN1(x)
        ln_kernel<<<BT, 256, 0, stream>>>(x, ln1_w + oE, ln1_b + oE, h);
        // q,k,v = h @ Wq/Wk/Wv
        gemm_f32<0,0><<<gE, 256, 0, stream>>>(h, wq + oEE, nullptr, nullptr, q, BT, EE, EE);
        gemm_f32<0,0><<<gE, 256, 0, stream>>>(h, wk + oEE, nullptr, nullptr, k, BT, EE, EE);
        gemm_f32<0,0><<<gE, 256, 0, stream>>>(h, wv + oEE, nullptr, nullptr, v, BT, EE, EE);
        // h = attention(q,k,v)   (h free after qkv GEMMs)
        attn_kernel<<<dim3(TT, HH, BB), 256, 0, stream>>>(q, k, v, h);
        // x = x + h @ Wo + bo
        gemm_f32<0,1><<<gE, 256, 0, stream>>>(h, wo + oEE, bo + oE, x, x, BT, EE, EE);
        // q = LN2(x)   (q free)
        ln_kernel<<<BT, 256, 0, stream>>>(x, ln2_w + oE, ln2_b + oE, q);
        // ffh = relu(q @ W1 + b1)
        gemm_f32<1,0><<<gF, 256, 0, stream>>>(q, w1 + oEF, b1 + (size_t)l*4*EE, nullptr, ffh, BT, 4*EE, EE);
        // x = x + ffh @ W2 + b2
        gemm_f32<0,1><<<gE, 256, 0, stream>>>(ffh, w2 + oEF, b2 + oE, x, x, BT, EE, 4*EE);
    }

    // h = LN_f(x); out = h @ head_w + head_b
    ln_kernel<<<BT, 256, 0, stream>>>(x, lnf_w, lnf_b, h);
    gemm_f32<0,0><<<gV, 256, 0, stream>>>(h, head_w, head_b, nullptr, out, BT, VV, EE);
}

// Round 2
// 3288.299 us; speedup vs baseline: 7.4027x; 7.4027x over previous
//
#include <hip/hip_runtime.h>
#include <hip/hip_bf16.h>
#include <math.h>

// Problem constants (SimpleLM): L=6, B=4, T=1024, V=32000, E=768, H=12, D=64
#define L_LAYERS 6
#define BB 4
#define TT 1024
#define VV 32000
#define EE 768
#define HH 12
#define DD 64
#define BT (BB * TT)          // 4096 rows of activations

typedef unsigned short u16;
typedef unsigned int   u32;
typedef __attribute__((ext_vector_type(8))) short short8;
typedef __attribute__((ext_vector_type(8))) unsigned short ushort8v;
typedef __attribute__((ext_vector_type(4))) float f32x4;

__device__ __forceinline__ float b2f_lo(u32 u) { union { u32 i; float f; } c; c.i = u << 16;          return c.f; }
__device__ __forceinline__ float b2f_hi(u32 u) { union { u32 i; float f; } c; c.i = u & 0xffff0000u;  return c.f; }
__device__ __forceinline__ u16  f2b(float f)   { union { float f; u32 i; } c{f}; u32 r = c.i + 0x7fffu + ((c.i >> 16) & 1u); return (u16)(r >> 16); }

__device__ __forceinline__ void gload16(const void* g, void* l) {
    __builtin_amdgcn_global_load_lds(
        (const __attribute__((address_space(1))) void*)g,
        (__attribute__((address_space(3))) void*)l, 16, 0, 0);
}

// ---------------------------------------------------------------------------
// Embedding: x[b,t,e] = tok_emb[idx[b,t], e] + pos_emb[t, e]  (f32 out)
// ---------------------------------------------------------------------------
__global__ __launch_bounds__(256) void embed_kernel(
    const int* __restrict__ idx, const float* __restrict__ tok_emb,
    const float* __restrict__ pos_emb, float* __restrict__ x)
{
    int i = blockIdx.x * 256 + threadIdx.x;          // < BT*EE
    int e  = i % EE;
    int bt = i / EE;
    int t  = bt % TT;
    int tok = idx[bt];
    x[i] = tok_emb[(size_t)tok * EE + e] + pos_emb[(size_t)t * EE + e];
}

// ---------------------------------------------------------------------------
// LayerNorm over last dim (E=768). f32 in, bf16 out. One block per row.
// ---------------------------------------------------------------------------
__global__ __launch_bounds__(256) void ln_kernel(
    const float* __restrict__ X, const float* __restrict__ w,
    const float* __restrict__ b, u16* __restrict__ Y)
{
    const int tid = threadIdx.x;
    const size_t row = blockIdx.x;
    const float* x = X + row * EE;

    float v0 = x[tid], v1 = x[tid + 256], v2 = x[tid + 512];

    __shared__ float red[256];
    red[tid] = v0 + v1 + v2;
    __syncthreads();
    for (int off = 128; off > 0; off >>= 1) {
        if (tid < off) red[tid] += red[tid + off];
        __syncthreads();
    }
    float mean = red[0] * (1.0f / EE);
    __syncthreads();
    float d0 = v0 - mean, d1 = v1 - mean, d2 = v2 - mean;
    red[tid] = d0 * d0 + d1 * d1 + d2 * d2;
    __syncthreads();
    for (int off = 128; off > 0; off >>= 1) {
        if (tid < off) red[tid] += red[tid + off];
        __syncthreads();
    }
    float rstd = rsqrtf(red[0] * (1.0f / EE) + 1e-5f);

    u16* y = Y + row * EE;
    y[tid]       = f2b(d0 * rstd * w[tid]       + b[tid]);
    y[tid + 256] = f2b(d1 * rstd * w[tid + 256] + b[tid + 256]);
    y[tid + 512] = f2b(d2 * rstd * w[tid + 512] + b[tid + 512]);
}

// ---------------------------------------------------------------------------
// Transpose + convert: W f32 [K,N] -> Wt bf16 [N,K]. 32x32 tiles.
// ---------------------------------------------------------------------------
__global__ __launch_bounds__(256) void transpose_cvt(
    const float* __restrict__ W, u16* __restrict__ Wt, int K, int N)
{
    __shared__ float t[32][33];
    const int k0 = blockIdx.y * 32;
    const int n0 = blockIdx.x * 32;
    const int c = threadIdx.x & 31;
    const int r = threadIdx.x >> 5;   // 0..7
    #pragma unroll
    for (int i = 0; i < 4; i++)
        t[r + i * 8][c] = W[(size_t)(k0 + r + i * 8) * N + n0 + c];
    __syncthreads();
    #pragma unroll
    for (int i = 0; i < 4; i++) {
        int rr = r + i * 8;
        Wt[(size_t)(n0 + rr) * K + k0 + c] = f2b(t[c][rr]);
    }
}

// ---------------------------------------------------------------------------
// bf16 MFMA GEMM: C[M,N] = A[M,K] @ Bt[N,K]^T  (+bias) (+res) (+relu)
// 128x128 tile, BK=64, 256 threads = 4 waves (2x2), 16x16x32 MFMA.
// LDS XOR-swizzled (chunk ^= row&7) via pre-swizzled global_load_lds source.
// ---------------------------------------------------------------------------
template<int RELU, int RES, int OUTBF>
__global__ __launch_bounds__(256) void gemm_bf16(
    const u16* __restrict__ A,    // [M,K] bf16
    const u16* __restrict__ Bt,   // [N,K] bf16
    const float* __restrict__ bias,
    const float* __restrict__ res,
    void* __restrict__ Cv,
    int M, int N, int K)
{
    __shared__ u16 As[128 * 64];
    __shared__ u16 Bs[128 * 64];

    const int tid  = threadIdx.x;
    const int lane = tid & 63;
    const int w    = tid >> 6;          // wave 0..3
    const int wr   = w >> 1, wc = w & 1;
    const int m0 = blockIdx.y * 128;
    const int n0 = blockIdx.x * 128;

    // staging source swizzle: LDS[row][chunk] holds G[row][chunk ^ (row&7)]
    const int cs = (lane & 7) ^ (lane >> 3);   // source chunk for this lane
    const int rl = lane >> 3;                  // 0..7 row-within-segment

    // fragment read offsets (ushort units), constant across K-loop
    int aoff[8], boff[8];
    const int kq = lane >> 4;                  // 0..3
    #pragma unroll
    for (int mi = 0; mi < 4; mi++) {
        int rg = wr * 64 + mi * 16 + (lane & 15);
        #pragma unroll
        for (int ks = 0; ks < 2; ks++)
            aoff[2 * mi + ks] = rg * 64 + (((ks * 4 + kq) ^ (rg & 7)) * 8);
    }
    #pragma unroll
    for (int ni = 0; ni < 4; ni++) {
        int rg = wc * 64 + ni * 16 + (lane & 15);
        #pragma unroll
        for (int ks = 0; ks < 2; ks++)
            boff[2 * ni + ks] = rg * 64 + (((ks * 4 + kq) ^ (rg & 7)) * 8);
    }

    f32x4 acc[4][4] = {};

    for (int k0 = 0; k0 < K; k0 += 64) {
        __syncthreads();
        #pragma unroll
        for (int i = 0; i < 4; i++) {
            const int seg = i * 4 + w;          // 0..15
            const int row = seg * 8 + rl;       // 0..127
            gload16(A  + (size_t)(m0 + row) * K + k0 + cs * 8, &As[seg * 512]);
            gload16(Bt + (size_t)(n0 + row) * K + k0 + cs * 8, &Bs[seg * 512]);
        }
        __syncthreads();
        #pragma unroll
        for (int ks = 0; ks < 2; ks++) {
            short8 af[4], bfv[4];
            #pragma unroll
            for (int mi = 0; mi < 4; mi++) af[mi]  = *(const short8*)&As[aoff[2 * mi + ks]];
            #pragma unroll
            for (int ni = 0; ni < 4; ni++) bfv[ni] = *(const short8*)&Bs[boff[2 * ni + ks]];
            #pragma unroll
            for (int mi = 0; mi < 4; mi++)
                #pragma unroll
                for (int ni = 0; ni < 4; ni++)
                    acc[mi][ni] = __builtin_amdgcn_mfma_f32_16x16x32_bf16(
                        af[mi], bfv[ni], acc[mi][ni], 0, 0, 0);
        }
    }

    // epilogue: C/D layout col=lane&15, row=(lane>>4)*4+i
    const int rbase = m0 + wr * 64 + (lane >> 4) * 4;
    const int cbase = n0 + wc * 64 + (lane & 15);
    #pragma unroll
    for (int ni = 0; ni < 4; ni++) {
        const int c = cbase + ni * 16;
        const float bv = bias ? bias[c] : 0.0f;
        #pragma unroll
        for (int mi = 0; mi < 4; mi++) {
            const int r = rbase + mi * 16;
            #pragma unroll
            for (int i = 0; i < 4; i++) {
                float v = acc[mi][ni][i] + bv;
                const size_t off = (size_t)(r + i) * N + c;
                if (RES)  v += res[off];
                if (RELU) v = fmaxf(v, 0.0f);
                if (OUTBF) ((u16*)Cv)[off] = f2b(v);
                else       ((float*)Cv)[off] = v;
            }
        }
    }
}

// ---------------------------------------------------------------------------
// Flash attention: block per (q-tile 64, h, b). 256 threads.
// qkv bf16 [BT, 2304] (q|k|v, col = h*64+d). Output bf16 [BT, 768].
// Thread (r=tid>>2, qc=tid&3): owns q-row r, k-slice qc+4j, d-slice qc*16..+16.
// ---------------------------------------------------------------------------
__global__ __launch_bounds__(256) void attn_flash(
    const u16* __restrict__ qkv, u16* __restrict__ O)
{
    const int tid = threadIdx.x;
    const int qi = blockIdx.x;
    const int h  = blockIdx.y;
    const int b  = blockIdx.z;
    const int q0 = qi * 64;

    __shared__ u16  Qs[64 * 72];
    __shared__ u16  Ks[64 * 72];
    __shared__ u16  Vs[64 * 72];
    __shared__ float Ss[64 * 65];

    const int r  = tid >> 2;    // 0..63
    const int qc = tid & 3;

    // stage Q tile (bf16 copy, padded rows)
    {
        const u16* src = qkv + (size_t)(b * TT + q0 + r) * 2304 + h * 64 + qc * 16;
        *(ushort8v*)&Qs[r * 72 + qc * 16]     = *(const ushort8v*)src;
        *(ushort8v*)&Qs[r * 72 + qc * 16 + 8] = *(const ushort8v*)(src + 8);
    }

    float Oa[16] = {};
    float m_run = -INFINITY, l_run = 0.0f;
    const int ntile = qi + 1;

    for (int t = 0; t < ntile; t++) {
        const int k0 = t * 64;
        __syncthreads();
        {
            const u16* ks = qkv + (size_t)(b * TT + k0 + r) * 2304 + 768 + h * 64 + qc * 16;
            *(ushort8v*)&Ks[r * 72 + qc * 16]     = *(const ushort8v*)ks;
            *(ushort8v*)&Ks[r * 72 + qc * 16 + 8] = *(const ushort8v*)(ks + 8);
            const u16* vs = ks + 768;
            *(ushort8v*)&Vs[r * 72 + qc * 16]     = *(const ushort8v*)vs;
            *(ushort8v*)&Vs[r * 72 + qc * 16 + 8] = *(const ushort8v*)(vs + 8);
        }
        __syncthreads();

        // scores for k = qc + 4j
        float sv[16];
        const u32* qrow = (const u32*)&Qs[r * 72];
        #pragma unroll
        for (int j = 0; j < 16; j++) {
            const int k = qc + 4 * j;
            const u32* krow = (const u32*)&Ks[k * 72];
            float acc = 0.0f;
            #pragma unroll
            for (int d2 = 0; d2 < 32; d2++) {
                const u32 qu = qrow[d2], ku = krow[d2];
                acc = fmaf(b2f_lo(qu), b2f_lo(ku), acc);
                acc = fmaf(b2f_hi(qu), b2f_hi(ku), acc);
            }
            acc *= 0.125f;                       // D^-0.5
            if (t == qi && k > r) acc = -INFINITY;  // causal (diag tile)
            sv[j] = acc;
        }

        // online softmax (4-lane groups per q-row)
        float pm = sv[0];
        #pragma unroll
        for (int j = 1; j < 16; j++) pm = fmaxf(pm, sv[j]);
        pm = fmaxf(pm, __shfl_xor(pm, 1, 4));
        pm = fmaxf(pm, __shfl_xor(pm, 2, 4));
        const float m_new = fmaxf(m_run, pm);
        const float scale = __expf(m_run - m_new);
        float ssum = 0.0f;
        #pragma unroll
        for (int j = 0; j < 16; j++) {
            const float p = __expf(sv[j] - m_new);
            sv[j] = p;
            ssum += p;
        }
        ssum += __shfl_xor(ssum, 1, 4);
        ssum += __shfl_xor(ssum, 2, 4);
        l_run = l_run * scale + ssum;
        m_run = m_new;
        #pragma unroll
        for (int i = 0; i < 16; i++) Oa[i] *= scale;

        #pragma unroll
        for (int j = 0; j < 16; j++) Ss[r * 65 + qc + 4 * j] = sv[j];
        __syncthreads();

        // PV: O[r][qc*16 + 0..15] += sum_k P[r][k] * V[k][d]
        for (int k = 0; k < 64; k++) {
            const float p = Ss[r * 65 + k];
            const u32* vrow = (const u32*)&Vs[k * 72 + qc * 16];
            #pragma unroll
            for (int j2 = 0; j2 < 8; j2++) {
                const u32 vu = vrow[j2];
                Oa[2 * j2]     = fmaf(p, b2f_lo(vu), Oa[2 * j2]);
                Oa[2 * j2 + 1] = fmaf(p, b2f_hi(vu), Oa[2 * j2 + 1]);
            }
        }
    }

    const float inv = 1.0f / l_run;
    u16* dst = O + (size_t)(b * TT + q0 + r) * 768 + h * 64 + qc * 16;
    #pragma unroll
    for (int i = 0; i < 16; i++) dst[i] = f2b(Oa[i] * inv);
}

// ---------------------------------------------------------------------------
// Host-side launch
// ---------------------------------------------------------------------------
extern "C" void kernel_launch(void* const* d_in, const int* in_sizes, int n_in,
                              void* d_out, int out_size, void* d_ws, size_t ws_size,
                              hipStream_t stream)
{
    (void)in_sizes; (void)n_in; (void)out_size; (void)ws_size;

    const int*   idx     = (const int*)  d_in[0];
    const float* tok_emb = (const float*)d_in[1];
    const float* pos_emb = (const float*)d_in[2];
    const float* ln1_w   = (const float*)d_in[3];
    const float* ln1_b   = (const float*)d_in[4];
    const float* wq      = (const float*)d_in[5];
    const float* wk      = (const float*)d_in[6];
    const float* wv      = (const float*)d_in[7];
    const float* wo      = (const float*)d_in[8];
    const float* bo      = (const float*)d_in[9];
    const float* ln2_w   = (const float*)d_in[10];
    const float* ln2_b   = (const float*)d_in[11];
    const float* w1      = (const float*)d_in[12];
    const float* b1      = (const float*)d_in[13];
    const float* w2      = (const float*)d_in[14];
    const float* b2      = (const float*)d_in[15];
    const float* lnf_w   = (const float*)d_in[16];
    const float* lnf_b   = (const float*)d_in[17];
    const float* head_w  = (const float*)d_in[18];
    const float* head_b  = (const float*)d_in[19];
    float* out = (float*)d_out;

    // workspace carve: ~112 MB
    const size_t S = (size_t)BT * EE;                 // 3,145,728
    float* x   = (float*)d_ws;                        // f32 [BT,768]
    u16*  qkv  = (u16*)(x + S);                       // bf16 [BT,2304]
    u16*  hb   = qkv + (size_t)BT * 2304;             // bf16 [BT,768]
    u16*  ffh  = hb + S;                              // bf16 [BT,3072]
    u16*  wt   = ffh + (size_t)BT * 3072;             // bf16 weights, reused per layer

    embed_kernel<<<BT * EE / 256, 256, 0, stream>>>(idx, tok_emb, pos_emb, x);

    auto T3 = [&](const float* W, u16* Wt, int K, int N) {
        transpose_cvt<<<dim3(N / 32, K / 32), 256, 0, stream>>>(W, Wt, K, N);
    };

    for (int l = 0; l < L_LAYERS; l++) {
        const size_t oE  = (size_t)l * EE;
        const size_t oEE = (size_t)l * EE * EE;
        const size_t oEF = (size_t)l * EE * 4 * EE;

        // weight prep (bf16, transposed, concatenated QKV)
        T3(wq + oEE, wt + 0,               EE, EE);
        T3(wk + oEE, wt + 768 * 768,       EE, EE);
        T3(wv + oEE, wt + 2 * 768 * 768,   EE, EE);
        T3(wo + oEE, wt + (size_t)2304 * 768, EE, EE);
        T3(w1 + oEF, wt + (size_t)3072 * 768, EE, 4 * EE);
        T3(w2 + oEF, wt + (size_t)6144 * 768, 4 * EE, EE);

        // h = LN1(x)
        ln_kernel<<<BT, 256, 0, stream>>>(x, ln1_w + oE, ln1_b + oE, hb);
        // qkv = h @ [Wq|Wk|Wv]   (bf16 out)
        gemm_bf16<0, 0, 1><<<dim3(2304 / 128, BT / 128), 256, 0, stream>>>(
            hb, wt, nullptr, nullptr, qkv, BT, 2304, 768);
        // h = attention(qkv)
        attn_flash<<<dim3(TT / 64, HH, BB), 256, 0, stream>>>(qkv, hb);
        // x = x + h @ Wo + bo
        gemm_bf16<0, 1, 0><<<dim3(768 / 128, BT / 128), 256, 0, stream>>>(
            hb, wt + (size_t)2304 * 768, bo + oE, x, x, BT, 768, 768);
        // h = LN2(x)
        ln_kernel<<<BT, 256, 0, stream>>>(x, ln2_w + oE, ln2_b + oE, hb);
        // ffh = relu(h @ W1 + b1)  (bf16 out)
        gemm_bf16<1, 0, 1><<<dim3(3072 / 128, BT / 128), 256, 0, stream>>>(
            hb, wt + (size_t)3072 * 768, b1 + (size_t)l * 4 * EE, nullptr, ffh, BT, 3072, 768);
        // x = x + ffh @ W2 + b2
        gemm_bf16<0, 1, 0><<<dim3(768 / 128, BT / 128), 256, 0, stream>>>(
            ffh, wt + (size_t)6144 * 768, b2 + oE, x, x, BT, 768, 3072);
    }

    // final LN + head
    ln_kernel<<<BT, 256, 0, stream>>>(x, lnf_w, lnf_b, hb);
    T3(head_w, wt, EE, VV);
    gemm_bf16<0, 0, 0><<<dim3(VV / 128, BT / 128), 256, 0, stream>>>(
        hb, wt, head_b, nullptr, out, BT, VV, 768);
}

// Round 3
// 3052.565 us; speedup vs baseline: 7.9743x; 1.0772x over previous
//
#include <hip/hip_runtime.h>
#include <hip/hip_bf16.h>
#include <math.h>

// Problem constants (SimpleLM): L=6, B=4, T=1024, V=32000, E=768, H=12, D=64
#define L_LAYERS 6
#define BB 4
#define TT 1024
#define VV 32000
#define EE 768
#define HH 12
#define DD 64
#define BT (BB * TT)          // 4096 rows of activations

typedef unsigned short u16;
typedef unsigned int   u32;
typedef __attribute__((ext_vector_type(8))) short short8;
typedef __attribute__((ext_vector_type(8))) unsigned short ushort8v;
typedef __attribute__((ext_vector_type(4))) float f32x4;

__device__ __forceinline__ float b2f_lo(u32 u) { union { u32 i; float f; } c; c.i = u << 16;          return c.f; }
__device__ __forceinline__ float b2f_hi(u32 u) { union { u32 i; float f; } c; c.i = u & 0xffff0000u;  return c.f; }
__device__ __forceinline__ u16  f2b(float f)   { union { float f; u32 i; } c{f}; u32 r = c.i + 0x7fffu + ((c.i >> 16) & 1u); return (u16)(r >> 16); }

__device__ __forceinline__ void gload16(const void* g, void* l) {
    __builtin_amdgcn_global_load_lds(
        (const __attribute__((address_space(1))) void*)g,
        (__attribute__((address_space(3))) void*)l, 16, 0, 0);
}

// ---------------------------------------------------------------------------
// Embedding: x[b,t,e] = tok_emb[idx[b,t], e] + pos_emb[t, e]  (f32 out)
// ---------------------------------------------------------------------------
__global__ __launch_bounds__(256) void embed_kernel(
    const int* __restrict__ idx, const float* __restrict__ tok_emb,
    const float* __restrict__ pos_emb, float* __restrict__ x)
{
    int i = blockIdx.x * 256 + threadIdx.x;          // < BT*EE
    int e  = i % EE;
    int bt = i / EE;
    int t  = bt % TT;
    int tok = idx[bt];
    x[i] = tok_emb[(size_t)tok * EE + e] + pos_emb[(size_t)t * EE + e];
}

// ---------------------------------------------------------------------------
// LayerNorm over last dim (E=768). f32 in, bf16 out. One block per row.
// ---------------------------------------------------------------------------
__global__ __launch_bounds__(256) void ln_kernel(
    const float* __restrict__ X, const float* __restrict__ w,
    const float* __restrict__ b, u16* __restrict__ Y)
{
    const int tid = threadIdx.x;
    const size_t row = blockIdx.x;
    const float* x = X + row * EE;

    float v0 = x[tid], v1 = x[tid + 256], v2 = x[tid + 512];

    __shared__ float red[256];
    red[tid] = v0 + v1 + v2;
    __syncthreads();
    for (int off = 128; off > 0; off >>= 1) {
        if (tid < off) red[tid] += red[tid + off];
        __syncthreads();
    }
    float mean = red[0] * (1.0f / EE);
    __syncthreads();
    float d0 = v0 - mean, d1 = v1 - mean, d2 = v2 - mean;
    red[tid] = d0 * d0 + d1 * d1 + d2 * d2;
    __syncthreads();
    for (int off = 128; off > 0; off >>= 1) {
        if (tid < off) red[tid] += red[tid + off];
        __syncthreads();
    }
    float rstd = rsqrtf(red[0] * (1.0f / EE) + 1e-5f);

    u16* y = Y + row * EE;
    y[tid]       = f2b(d0 * rstd * w[tid]       + b[tid]);
    y[tid + 256] = f2b(d1 * rstd * w[tid + 256] + b[tid + 256]);
    y[tid + 512] = f2b(d2 * rstd * w[tid + 512] + b[tid + 512]);
}

// ---------------------------------------------------------------------------
// Transpose + convert 32x32 tile core: W f32 [K,N] -> Wt bf16 [N,K]
// ---------------------------------------------------------------------------
__device__ __forceinline__ void transpose_tile(
    const float* __restrict__ W, u16* __restrict__ Wt,
    int K, int N, int kt, int nt)
{
    __shared__ float t[32][33];
    const int k0 = kt * 32;
    const int n0 = nt * 32;
    const int c = threadIdx.x & 31;
    const int r = threadIdx.x >> 5;   // 0..7
    #pragma unroll
    for (int i = 0; i < 4; i++)
        t[r + i * 8][c] = W[(size_t)(k0 + r + i * 8) * N + n0 + c];
    __syncthreads();
    #pragma unroll
    for (int i = 0; i < 4; i++) {
        int rr = r + i * 8;
        Wt[(size_t)(n0 + rr) * K + k0 + c] = f2b(t[c][rr]);
    }
}

// Single-matrix transpose (used for head_w)
__global__ __launch_bounds__(256) void transpose_cvt(
    const float* __restrict__ W, u16* __restrict__ Wt, int K, int N)
{
    transpose_tile(W, Wt, K, N, blockIdx.y, blockIdx.x);
}

// Batched per-layer transpose: wq,wk,wv,wo (768x768 each), w1 (768x3072),
// w2 (3072x768) -> wt = [wqT|wkT|wvT|woT|w1T|w2T]. 6912 tiles total.
__global__ __launch_bounds__(256) void transpose_layer(
    const float* __restrict__ wq, const float* __restrict__ wk,
    const float* __restrict__ wv, const float* __restrict__ wo,
    const float* __restrict__ w1, const float* __restrict__ w2,
    u16* __restrict__ wt)
{
    const int t = blockIdx.x;
    if (t < 2304) {                       // 4 x (768x768), 576 tiles each
        const int m = t / 576, r = t % 576;
        const float* Ws[4] = {wq, wk, wv, wo};
        transpose_tile(Ws[m], wt + (size_t)m * 768 * 768, 768, 768, r / 24, r % 24);
    } else if (t < 4608) {                // w1: K=768, N=3072 -> w1T [3072,768]
        const int r = t - 2304;
        transpose_tile(w1, wt + (size_t)4 * 768 * 768, 768, 3072, r / 96, r % 96);
    } else {                              // w2: K=3072, N=768 -> w2T [768,3072]
        const int r = t - 4608;
        transpose_tile(w2, wt + (size_t)4 * 768 * 768 + (size_t)3072 * 768,
                       3072, 768, r / 24, r % 24);
    }
}

// ---------------------------------------------------------------------------
// bf16 MFMA GEMM: C[M,N] = A[M,K] @ Bt[N,K]^T  (+bias) (+res) (+relu)
// Tile (32*MFRAG) x 128, BK=64, 256 threads = 4 waves, 16x16x32 MFMA.
// Grid: x = M-tiles (fast, shares B-panel across concurrent blocks), y = N-tiles.
// LDS XOR-swizzled (chunk ^= row&7) via pre-swizzled global_load_lds source.
// ---------------------------------------------------------------------------
template<int RELU, int RES, int OUTBF, int MFRAG>   // MFRAG: 16-row frags per wave (4 -> TM=128, 2 -> TM=64)
__global__ __launch_bounds__(256) void gemm_bf16(
    const u16* __restrict__ A,    // [M,K] bf16
    const u16* __restrict__ Bt,   // [N,K] bf16
    const float* __restrict__ bias,
    const float* __restrict__ res,
    void* __restrict__ Cv,
    int M, int N, int K)
{
    constexpr int TM = MFRAG * 32;          // block M rows
    __shared__ u16 As[TM * 64];
    __shared__ u16 Bs[128 * 64];

    const int tid  = threadIdx.x;
    const int lane = tid & 63;
    const int w    = tid >> 6;          // wave 0..3
    const int wr   = w >> 1, wc = w & 1;
    const int m0 = blockIdx.x * TM;     // M is the fast grid dim
    const int n0 = blockIdx.y * 128;

    // staging source swizzle: LDS[row][chunk] holds G[row][chunk ^ (row&7)]
    const int cs = (lane & 7) ^ (lane >> 3);   // source chunk for this lane
    const int rl = lane >> 3;                  // 0..7 row-within-segment

    // fragment read offsets (ushort units), constant across K-loop
    int aoff[2 * MFRAG], boff[8];
    const int kq = lane >> 4;                  // 0..3
    #pragma unroll
    for (int mi = 0; mi < MFRAG; mi++) {
        int rg = wr * (MFRAG * 16) + mi * 16 + (lane & 15);
        #pragma unroll
        for (int ks = 0; ks < 2; ks++)
            aoff[2 * mi + ks] = rg * 64 + (((ks * 4 + kq) ^ (rg & 7)) * 8);
    }
    #pragma unroll
    for (int ni = 0; ni < 4; ni++) {
        int rg = wc * 64 + ni * 16 + (lane & 15);
        #pragma unroll
        for (int ks = 0; ks < 2; ks++)
            boff[2 * ni + ks] = rg * 64 + (((ks * 4 + kq) ^ (rg & 7)) * 8);
    }

    f32x4 acc[MFRAG][4] = {};

    for (int k0 = 0; k0 < K; k0 += 64) {
        __syncthreads();
        #pragma unroll
        for (int i = 0; i < MFRAG; i++) {       // A: TM/8 segments
            const int seg = i * 4 + w;
            const int row = seg * 8 + rl;
            gload16(A + (size_t)(m0 + row) * K + k0 + cs * 8, &As[seg * 512]);
        }
        #pragma unroll
        for (int i = 0; i < 4; i++) {           // B: 16 segments
            const int seg = i * 4 + w;
            const int row = seg * 8 + rl;
            gload16(Bt + (size_t)(n0 + row) * K + k0 + cs * 8, &Bs[seg * 512]);
        }
        __syncthreads();
        #pragma unroll
        for (int ks = 0; ks < 2; ks++) {
            short8 af[MFRAG], bfv[4];
            #pragma unroll
            for (int mi = 0; mi < MFRAG; mi++) af[mi] = *(const short8*)&As[aoff[2 * mi + ks]];
            #pragma unroll
            for (int ni = 0; ni < 4; ni++) bfv[ni] = *(const short8*)&Bs[boff[2 * ni + ks]];
            #pragma unroll
            for (int mi = 0; mi < MFRAG; mi++)
                #pragma unroll
                for (int ni = 0; ni < 4; ni++)
                    acc[mi][ni] = __builtin_amdgcn_mfma_f32_16x16x32_bf16(
                        af[mi], bfv[ni], acc[mi][ni], 0, 0, 0);
        }
    }

    // epilogue: C/D layout col=lane&15, row=(lane>>4)*4+i
    const int rbase = m0 + wr * (MFRAG * 16) + (lane >> 4) * 4;
    const int cbase = n0 + wc * 64 + (lane & 15);
    #pragma unroll
    for (int ni = 0; ni < 4; ni++) {
        const int c = cbase + ni * 16;
        const float bv = bias ? bias[c] : 0.0f;
        #pragma unroll
        for (int mi = 0; mi < MFRAG; mi++) {
            const int r = rbase + mi * 16;
            #pragma unroll
            for (int i = 0; i < 4; i++) {
                float v = acc[mi][ni][i] + bv;
                const size_t off = (size_t)(r + i) * N + c;
                if (RES)  v += res[off];
                if (RELU) v = fmaxf(v, 0.0f);
                if (OUTBF) ((u16*)Cv)[off] = f2b(v);
                else       ((float*)Cv)[off] = v;
            }
        }
    }
}

// ---------------------------------------------------------------------------
// Flash attention: block per (q-tile 64, h, b). 256 threads.
// qkv bf16 [BT, 2304] (q|k|v, col = h*64+d). Output bf16 [BT, 768].
// Thread (r=tid>>2, qc=tid&3): owns q-row r, k-slice qc+4j, d-slice qc*16..+16.
// ---------------------------------------------------------------------------
__global__ __launch_bounds__(256) void attn_flash(
    const u16* __restrict__ qkv, u16* __restrict__ O)
{
    const int tid = threadIdx.x;
    const int qi = blockIdx.x;
    const int h  = blockIdx.y;
    const int b  = blockIdx.z;
    const int q0 = qi * 64;

    __shared__ u16  Qs[64 * 72];
    __shared__ u16  Ks[64 * 72];
    __shared__ u16  Vs[64 * 72];
    __shared__ float Ss[64 * 65];

    const int r  = tid >> 2;    // 0..63
    const int qc = tid & 3;

    // stage Q tile (bf16 copy, padded rows)
    {
        const u16* src = qkv + (size_t)(b * TT + q0 + r) * 2304 + h * 64 + qc * 16;
        *(ushort8v*)&Qs[r * 72 + qc * 16]     = *(const ushort8v*)src;
        *(ushort8v*)&Qs[r * 72 + qc * 16 + 8] = *(const ushort8v*)(src + 8);
    }

    float Oa[16] = {};
    float m_run = -INFINITY, l_run = 0.0f;
    const int ntile = qi + 1;

    for (int t = 0; t < ntile; t++) {
        const int k0 = t * 64;
        __syncthreads();
        {
            const u16* ks = qkv + (size_t)(b * TT + k0 + r) * 2304 + 768 + h * 64 + qc * 16;
            *(ushort8v*)&Ks[r * 72 + qc * 16]     = *(const ushort8v*)ks;
            *(ushort8v*)&Ks[r * 72 + qc * 16 + 8] = *(const ushort8v*)(ks + 8);
            const u16* vs = ks + 768;
            *(ushort8v*)&Vs[r * 72 + qc * 16]     = *(const ushort8v*)vs;
            *(ushort8v*)&Vs[r * 72 + qc * 16 + 8] = *(const ushort8v*)(vs + 8);
        }
        __syncthreads();

        // scores for k = qc + 4j
        float sv[16];
        const u32* qrow = (const u32*)&Qs[r * 72];
        #pragma unroll
        for (int j = 0; j < 16; j++) {
            const int k = qc + 4 * j;
            const u32* krow = (const u32*)&Ks[k * 72];
            float acc = 0.0f;
            #pragma unroll
            for (int d2 = 0; d2 < 32; d2++) {
                const u32 qu = qrow[d2], ku = krow[d2];
                acc = fmaf(b2f_lo(qu), b2f_lo(ku), acc);
                acc = fmaf(b2f_hi(qu), b2f_hi(ku), acc);
            }
            acc *= 0.125f;                       // D^-0.5
            if (t == qi && k > r) acc = -INFINITY;  // causal (diag tile)
            sv[j] = acc;
        }

        // online softmax (4-lane groups per q-row)
        float pm = sv[0];
        #pragma unroll
        for (int j = 1; j < 16; j++) pm = fmaxf(pm, sv[j]);
        pm = fmaxf(pm, __shfl_xor(pm, 1, 4));
        pm = fmaxf(pm, __shfl_xor(pm, 2, 4));
        const float m_new = fmaxf(m_run, pm);
        const float scale = __expf(m_run - m_new);
        float ssum = 0.0f;
        #pragma unroll
        for (int j = 0; j < 16; j++) {
            const float p = __expf(sv[j] - m_new);
            sv[j] = p;
            ssum += p;
        }
        ssum += __shfl_xor(ssum, 1, 4);
        ssum += __shfl_xor(ssum, 2, 4);
        l_run = l_run * scale + ssum;
        m_run = m_new;
        #pragma unroll
        for (int i = 0; i < 16; i++) Oa[i] *= scale;

        #pragma unroll
        for (int j = 0; j < 16; j++) Ss[r * 65 + qc + 4 * j] = sv[j];
        __syncthreads();

        // PV: O[r][qc*16 + 0..15] += sum_k P[r][k] * V[k][d]
        for (int k = 0; k < 64; k++) {
            const float p = Ss[r * 65 + k];
            const u32* vrow = (const u32*)&Vs[k * 72 + qc * 16];
            #pragma unroll
            for (int j2 = 0; j2 < 8; j2++) {
                const u32 vu = vrow[j2];
                Oa[2 * j2]     = fmaf(p, b2f_lo(vu), Oa[2 * j2]);
                Oa[2 * j2 + 1] = fmaf(p, b2f_hi(vu), Oa[2 * j2 + 1]);
            }
        }
    }

    const float inv = 1.0f / l_run;
    u16* dst = O + (size_t)(b * TT + q0 + r) * 768 + h * 64 + qc * 16;
    #pragma unroll
    for (int i = 0; i < 16; i++) dst[i] = f2b(Oa[i] * inv);
}

// ---------------------------------------------------------------------------
// Host-side launch
// ---------------------------------------------------------------------------
extern "C" void kernel_launch(void* const* d_in, const int* in_sizes, int n_in,
                              void* d_out, int out_size, void* d_ws, size_t ws_size,
                              hipStream_t stream)
{
    (void)in_sizes; (void)n_in; (void)out_size; (void)ws_size;

    const int*   idx     = (const int*)  d_in[0];
    const float* tok_emb = (const float*)d_in[1];
    const float* pos_emb = (const float*)d_in[2];
    const float* ln1_w   = (const float*)d_in[3];
    const float* ln1_b   = (const float*)d_in[4];
    const float* wq      = (const float*)d_in[5];
    const float* wk      = (const float*)d_in[6];
    const float* wv      = (const float*)d_in[7];
    const float* wo      = (const float*)d_in[8];
    const float* bo      = (const float*)d_in[9];
    const float* ln2_w   = (const float*)d_in[10];
    const float* ln2_b   = (const float*)d_in[11];
    const float* w1      = (const float*)d_in[12];
    const float* b1      = (const float*)d_in[13];
    const float* w2      = (const float*)d_in[14];
    const float* b2      = (const float*)d_in[15];
    const float* lnf_w   = (const float*)d_in[16];
    const float* lnf_b   = (const float*)d_in[17];
    const float* head_w  = (const float*)d_in[18];
    const float* head_b  = (const float*)d_in[19];
    float* out = (float*)d_out;

    // workspace carve: ~112 MB
    const size_t S = (size_t)BT * EE;                 // 3,145,728
    float* x   = (float*)d_ws;                        // f32 [BT,768]
    u16*  qkv  = (u16*)(x + S);                       // bf16 [BT,2304]
    u16*  hb   = qkv + (size_t)BT * 2304;             // bf16 [BT,768]
    u16*  ffh  = hb + S;                              // bf16 [BT,3072]
    u16*  wt   = ffh + (size_t)BT * 3072;             // bf16 weights, reused per layer

    embed_kernel<<<BT * EE / 256, 256, 0, stream>>>(idx, tok_emb, pos_emb, x);

    for (int l = 0; l < L_LAYERS; l++) {
        const size_t oE  = (size_t)l * EE;
        const size_t oEE = (size_t)l * EE * EE;
        const size_t oEF = (size_t)l * EE * 4 * EE;

        // weight prep: all 6 matrices of this layer in one dispatch
        transpose_layer<<<6912, 256, 0, stream>>>(
            wq + oEE, wk + oEE, wv + oEE, wo + oEE, w1 + oEF, w2 + oEF, wt);

        // h = LN1(x)
        ln_kernel<<<BT, 256, 0, stream>>>(x, ln1_w + oE, ln1_b + oE, hb);
        // qkv = h @ [Wq|Wk|Wv]   (bf16 out)
        gemm_bf16<0, 0, 1, 4><<<dim3(BT / 128, 2304 / 128), 256, 0, stream>>>(
            hb, wt, nullptr, nullptr, qkv, BT, 2304, 768);
        // h = attention(qkv)
        attn_flash<<<dim3(TT / 64, HH, BB), 256, 0, stream>>>(qkv, hb);
        // x = x + h @ Wo + bo   (TM=64: 384 blocks)
        gemm_bf16<0, 1, 0, 2><<<dim3(BT / 64, 768 / 128), 256, 0, stream>>>(
            hb, wt + (size_t)3 * 768 * 768, bo + oE, x, x, BT, 768, 768);
        // h = LN2(x)
        ln_kernel<<<BT, 256, 0, stream>>>(x, ln2_w + oE, ln2_b + oE, hb);
        // ffh = relu(h @ W1 + b1)  (bf16 out)
        gemm_bf16<1, 0, 1, 4><<<dim3(BT / 128, 3072 / 128), 256, 0, stream>>>(
            hb, wt + (size_t)4 * 768 * 768, b1 + (size_t)l * 4 * EE, nullptr, ffh, BT, 3072, 768);
        // x = x + ffh @ W2 + b2   (TM=64: 384 blocks)
        gemm_bf16<0, 1, 0, 2><<<dim3(BT / 64, 768 / 128), 256, 0, stream>>>(
            ffh, wt + (size_t)4 * 768 * 768 + (size_t)3072 * 768, b2 + oE, x, x, BT, 768, 3072);
    }

    // final LN + head
    ln_kernel<<<BT, 256, 0, stream>>>(x, lnf_w, lnf_b, hb);
    transpose_cvt<<<dim3(VV / 32, EE / 32), 256, 0, stream>>>(head_w, wt, EE, VV);
    gemm_bf16<0, 0, 0, 4><<<dim3(BT / 128, VV / 128), 256, 0, stream>>>(
        hb, wt, head_b, nullptr, out, BT, VV, 768);
}

// Round 4
// 1566.975 us; speedup vs baseline: 15.5345x; 1.9481x over previous
//
#include <hip/hip_runtime.h>
#include <hip/hip_bf16.h>
#include <math.h>

// Problem constants (SimpleLM): L=6, B=4, T=1024, V=32000, E=768, H=12, D=64
#define L_LAYERS 6
#define BB 4
#define TT 1024
#define VV 32000
#define EE 768
#define HH 12
#define DD 64
#define BT (BB * TT)          // 4096 rows of activations

typedef unsigned short u16;
typedef unsigned int   u32;
typedef __attribute__((ext_vector_type(8))) short short8;
typedef __attribute__((ext_vector_type(8))) unsigned short ushort8v;
typedef __attribute__((ext_vector_type(4))) float f32x4;

__device__ __forceinline__ float b2f_lo(u32 u) { union { u32 i; float f; } c; c.i = u << 16;          return c.f; }
__device__ __forceinline__ float b2f_hi(u32 u) { union { u32 i; float f; } c; c.i = u & 0xffff0000u;  return c.f; }
__device__ __forceinline__ u16  f2b(float f)   { union { float f; u32 i; } c{f}; u32 r = c.i + 0x7fffu + ((c.i >> 16) & 1u); return (u16)(r >> 16); }

__device__ __forceinline__ void gload16(const void* g, void* l) {
    __builtin_amdgcn_global_load_lds(
        (const __attribute__((address_space(1))) void*)g,
        (__attribute__((address_space(3))) void*)l, 16, 0, 0);
}

// ---------------------------------------------------------------------------
// Embedding: x[b,t,e] = tok_emb[idx[b,t], e] + pos_emb[t, e]  (f32 out)
// ---------------------------------------------------------------------------
__global__ __launch_bounds__(256) void embed_kernel(
    const int* __restrict__ idx, const float* __restrict__ tok_emb,
    const float* __restrict__ pos_emb, float* __restrict__ x)
{
    int i = blockIdx.x * 256 + threadIdx.x;          // < BT*EE
    int e  = i % EE;
    int bt = i / EE;
    int t  = bt % TT;
    int tok = idx[bt];
    x[i] = tok_emb[(size_t)tok * EE + e] + pos_emb[(size_t)t * EE + e];
}

// ---------------------------------------------------------------------------
// LayerNorm over last dim (E=768). f32 in, bf16 out. One block per row.
// ---------------------------------------------------------------------------
__global__ __launch_bounds__(256) void ln_kernel(
    const float* __restrict__ X, const float* __restrict__ w,
    const float* __restrict__ b, u16* __restrict__ Y)
{
    const int tid = threadIdx.x;
    const size_t row = blockIdx.x;
    const float* x = X + row * EE;

    float v0 = x[tid], v1 = x[tid + 256], v2 = x[tid + 512];

    __shared__ float red[256];
    red[tid] = v0 + v1 + v2;
    __syncthreads();
    for (int off = 128; off > 0; off >>= 1) {
        if (tid < off) red[tid] += red[tid + off];
        __syncthreads();
    }
    float mean = red[0] * (1.0f / EE);
    __syncthreads();
    float d0 = v0 - mean, d1 = v1 - mean, d2 = v2 - mean;
    red[tid] = d0 * d0 + d1 * d1 + d2 * d2;
    __syncthreads();
    for (int off = 128; off > 0; off >>= 1) {
        if (tid < off) red[tid] += red[tid + off];
        __syncthreads();
    }
    float rstd = rsqrtf(red[0] * (1.0f / EE) + 1e-5f);

    u16* y = Y + row * EE;
    y[tid]       = f2b(d0 * rstd * w[tid]       + b[tid]);
    y[tid + 256] = f2b(d1 * rstd * w[tid + 256] + b[tid + 256]);
    y[tid + 512] = f2b(d2 * rstd * w[tid + 512] + b[tid + 512]);
}

// ---------------------------------------------------------------------------
// Transpose + convert 32x32 tile core: W f32 [K,N] -> Wt bf16 [N,K]
// ---------------------------------------------------------------------------
__device__ __forceinline__ void transpose_tile(
    const float* __restrict__ W, u16* __restrict__ Wt,
    int K, int N, int kt, int nt)
{
    __shared__ float t[32][33];
    const int k0 = kt * 32;
    const int n0 = nt * 32;
    const int c = threadIdx.x & 31;
    const int r = threadIdx.x >> 5;   // 0..7
    #pragma unroll
    for (int i = 0; i < 4; i++)
        t[r + i * 8][c] = W[(size_t)(k0 + r + i * 8) * N + n0 + c];
    __syncthreads();
    #pragma unroll
    for (int i = 0; i < 4; i++) {
        int rr = r + i * 8;
        Wt[(size_t)(n0 + rr) * K + k0 + c] = f2b(t[c][rr]);
    }
}

// Single-matrix transpose (used for head_w)
__global__ __launch_bounds__(256) void transpose_cvt(
    const float* __restrict__ W, u16* __restrict__ Wt, int K, int N)
{
    transpose_tile(W, Wt, K, N, blockIdx.y, blockIdx.x);
}

// Batched per-layer transpose: wq,wk,wv,wo (768x768 each), w1 (768x3072),
// w2 (3072x768) -> wt = [wqT|wkT|wvT|woT|w1T|w2T]. 6912 tiles total.
__global__ __launch_bounds__(256) void transpose_layer(
    const float* __restrict__ wq, const float* __restrict__ wk,
    const float* __restrict__ wv, const float* __restrict__ wo,
    const float* __restrict__ w1, const float* __restrict__ w2,
    u16* __restrict__ wt)
{
    const int t = blockIdx.x;
    if (t < 2304) {                       // 4 x (768x768), 576 tiles each
        const int m = t / 576, r = t % 576;
        const float* Ws[4] = {wq, wk, wv, wo};
        transpose_tile(Ws[m], wt + (size_t)m * 768 * 768, 768, 768, r / 24, r % 24);
    } else if (t < 4608) {                // w1: K=768, N=3072 -> w1T [3072,768]
        const int r = t - 2304;
        transpose_tile(w1, wt + (size_t)4 * 768 * 768, 768, 3072, r / 96, r % 96);
    } else {                              // w2: K=3072, N=768 -> w2T [768,3072]
        const int r = t - 4608;
        transpose_tile(w2, wt + (size_t)4 * 768 * 768 + (size_t)3072 * 768,
                       3072, 768, r / 24, r % 24);
    }
}

// ---------------------------------------------------------------------------
// bf16 MFMA GEMM: C[M,N] = A[M,K] @ Bt[N,K]^T  (+bias) (+res) (+relu)
// Tile (32*MFRAG) x 128, BK=64, 256 threads = 4 waves, 16x16x32 MFMA.
// Grid: x = M-tiles (fast, shares B-panel across concurrent blocks), y = N-tiles.
// LDS XOR-swizzled (chunk ^= row&7) via pre-swizzled global_load_lds source.
// ---------------------------------------------------------------------------
template<int RELU, int RES, int OUTBF, int MFRAG>   // MFRAG: 16-row frags per wave (4 -> TM=128, 2 -> TM=64)
__global__ __launch_bounds__(256) void gemm_bf16(
    const u16* __restrict__ A,    // [M,K] bf16
    const u16* __restrict__ Bt,   // [N,K] bf16
    const float* __restrict__ bias,
    const float* __restrict__ res,
    void* __restrict__ Cv,
    int M, int N, int K)
{
    constexpr int TM = MFRAG * 32;          // block M rows
    __shared__ u16 As[TM * 64];
    __shared__ u16 Bs[128 * 64];

    const int tid  = threadIdx.x;
    const int lane = tid & 63;
    const int w    = tid >> 6;          // wave 0..3
    const int wr   = w >> 1, wc = w & 1;
    const int m0 = blockIdx.x * TM;     // M is the fast grid dim
    const int n0 = blockIdx.y * 128;

    // staging source swizzle: LDS[row][chunk] holds G[row][chunk ^ (row&7)]
    const int cs = (lane & 7) ^ (lane >> 3);   // source chunk for this lane
    const int rl = lane >> 3;                  // 0..7 row-within-segment

    // fragment read offsets (ushort units), constant across K-loop
    int aoff[2 * MFRAG], boff[8];
    const int kq = lane >> 4;                  // 0..3
    #pragma unroll
    for (int mi = 0; mi < MFRAG; mi++) {
        int rg = wr * (MFRAG * 16) + mi * 16 + (lane & 15);
        #pragma unroll
        for (int ks = 0; ks < 2; ks++)
            aoff[2 * mi + ks] = rg * 64 + (((ks * 4 + kq) ^ (rg & 7)) * 8);
    }
    #pragma unroll
    for (int ni = 0; ni < 4; ni++) {
        int rg = wc * 64 + ni * 16 + (lane & 15);
        #pragma unroll
        for (int ks = 0; ks < 2; ks++)
            boff[2 * ni + ks] = rg * 64 + (((ks * 4 + kq) ^ (rg & 7)) * 8);
    }

    f32x4 acc[MFRAG][4] = {};

    for (int k0 = 0; k0 < K; k0 += 64) {
        __syncthreads();
        #pragma unroll
        for (int i = 0; i < MFRAG; i++) {       // A: TM/8 segments
            const int seg = i * 4 + w;
            const int row = seg * 8 + rl;
            gload16(A + (size_t)(m0 + row) * K + k0 + cs * 8, &As[seg * 512]);
        }
        #pragma unroll
        for (int i = 0; i < 4; i++) {           // B: 16 segments
            const int seg = i * 4 + w;
            const int row = seg * 8 + rl;
            gload16(Bt + (size_t)(n0 + row) * K + k0 + cs * 8, &Bs[seg * 512]);
        }
        __syncthreads();
        #pragma unroll
        for (int ks = 0; ks < 2; ks++) {
            short8 af[MFRAG], bfv[4];
            #pragma unroll
            for (int mi = 0; mi < MFRAG; mi++) af[mi] = *(const short8*)&As[aoff[2 * mi + ks]];
            #pragma unroll
            for (int ni = 0; ni < 4; ni++) bfv[ni] = *(const short8*)&Bs[boff[2 * ni + ks]];
            #pragma unroll
            for (int mi = 0; mi < MFRAG; mi++)
                #pragma unroll
                for (int ni = 0; ni < 4; ni++)
                    acc[mi][ni] = __builtin_amdgcn_mfma_f32_16x16x32_bf16(
                        af[mi], bfv[ni], acc[mi][ni], 0, 0, 0);
        }
    }

    // epilogue: C/D layout col=lane&15, row=(lane>>4)*4+i
    const int rbase = m0 + wr * (MFRAG * 16) + (lane >> 4) * 4;
    const int cbase = n0 + wc * 64 + (lane & 15);
    #pragma unroll
    for (int ni = 0; ni < 4; ni++) {
        const int c = cbase + ni * 16;
        const float bv = bias ? bias[c] : 0.0f;
        #pragma unroll
        for (int mi = 0; mi < MFRAG; mi++) {
            const int r = rbase + mi * 16;
            #pragma unroll
            for (int i = 0; i < 4; i++) {
                float v = acc[mi][ni][i] + bv;
                const size_t off = (size_t)(r + i) * N + c;
                if (RES)  v += res[off];
                if (RELU) v = fmaxf(v, 0.0f);
                if (OUTBF) ((u16*)Cv)[off] = f2b(v);
                else       ((float*)Cv)[off] = v;
            }
        }
    }
}

// ---------------------------------------------------------------------------
// MFMA flash attention: block per (q-tile 64, h, b). 256 threads = 4 waves.
// Wave w owns q-rows [w*16, w*16+16). QK^T and PV are 16x16x32 MFMAs.
// LDS tiles padded to stride 76 u16 (conflict-free b128 frag reads).
// V staged transposed (Vt[d][k]) so PV B-frag reads 8 contiguous k.
// Online softmax lives in the C-fragment (shfl over 16-lane groups).
// ---------------------------------------------------------------------------
#define AST 76
__global__ __launch_bounds__(256) void attn_mfma(
    const u16* __restrict__ qkv, u16* __restrict__ O)
{
    const int tid = threadIdx.x;
    const int qi = blockIdx.x;
    const int h  = blockIdx.y;
    const int b  = blockIdx.z;
    const int q0 = qi * 64;

    __shared__ u16 Ks[64 * AST];
    __shared__ u16 Vt[64 * AST];
    __shared__ u16 Ps[64 * AST];   // doubles as Q staging buffer

    const int lane = tid & 63;
    const int w    = tid >> 6;        // wave 0..3
    const int lr   = lane & 15;       // frag row/col
    const int lk   = lane >> 4;       // frag k-group (0..3)

    const int sr = tid >> 2;          // staging row 0..63
    const int sc = tid & 3;           // staging col-chunk (16 u16)

    // ---- stage Q into Ps, hoist A-fragments to registers ----
    {
        const u16* src = qkv + (size_t)(b * TT + q0 + sr) * 2304 + h * 64 + sc * 16;
        *(ushort8v*)&Ps[sr * AST + sc * 16]     = *(const ushort8v*)src;
        *(ushort8v*)&Ps[sr * AST + sc * 16 + 8] = *(const ushort8v*)(src + 8);
    }
    __syncthreads();
    short8 aq[2];
    #pragma unroll
    for (int ks = 0; ks < 2; ks++)
        aq[ks] = *(const short8*)&Ps[(w * 16 + lr) * AST + lk * 8 + ks * 32];

    f32x4 oacc[4] = {};               // [d-tile], 4 rows each
    float m_run[4], l_run[4];
    #pragma unroll
    for (int i = 0; i < 4; i++) { m_run[i] = -3.0e38f; l_run[i] = 0.0f; }

    const int qrow = q0 + w * 16 + lk * 4;     // + i = this lane's rows
    const int ntile = qi + 1;

    for (int t = 0; t < ntile; t++) {
        const int k0 = t * 64;
        __syncthreads();               // previous tile's LDS reads done
        // ---- stage K [k][d] and V^T [d][k] ----
        {
            const u16* ksrc = qkv + (size_t)(b * TT + k0 + sr) * 2304 + 768 + h * 64 + sc * 16;
            *(ushort8v*)&Ks[sr * AST + sc * 16]     = *(const ushort8v*)ksrc;
            *(ushort8v*)&Ks[sr * AST + sc * 16 + 8] = *(const ushort8v*)(ksrc + 8);
            const u16* vsrc = ksrc + 768;
            ushort8v v0 = *(const ushort8v*)vsrc;
            ushort8v v1 = *(const ushort8v*)(vsrc + 8);
            #pragma unroll
            for (int j = 0; j < 8; j++) Vt[(sc * 16 + j) * AST + sr]     = v0[j];
            #pragma unroll
            for (int j = 0; j < 8; j++) Vt[(sc * 16 + 8 + j) * AST + sr] = v1[j];
        }
        __syncthreads();

        // ---- QK^T: wave's 16 q-rows x 64 k-cols ----
        f32x4 sfrag[4] = {};
        #pragma unroll
        for (int ks = 0; ks < 2; ks++)
            #pragma unroll
            for (int nt = 0; nt < 4; nt++) {
                short8 bk = *(const short8*)&Ks[(nt * 16 + lr) * AST + lk * 8 + ks * 32];
                sfrag[nt] = __builtin_amdgcn_mfma_f32_16x16x32_bf16(aq[ks], bk, sfrag[nt], 0, 0, 0);
            }

        // ---- online softmax in C-frag ----
        float sv[4][4];
        #pragma unroll
        for (int i = 0; i < 4; i++) {
            float mx = -3.0e38f;
            #pragma unroll
            for (int nt = 0; nt < 4; nt++) {
                float s = sfrag[nt][i] * 0.125f;       // D^-0.5
                if (t == qi && (k0 + nt * 16 + lr) > (qrow + i)) s = -3.0e38f;
                sv[i][nt] = s;
                mx = fmaxf(mx, s);
            }
            mx = fmaxf(mx, __shfl_xor(mx, 1));
            mx = fmaxf(mx, __shfl_xor(mx, 2));
            mx = fmaxf(mx, __shfl_xor(mx, 4));
            mx = fmaxf(mx, __shfl_xor(mx, 8));
            const float m_new = fmaxf(m_run[i], mx);
            const float scale = __expf(m_run[i] - m_new);
            float rs = 0.0f;
            #pragma unroll
            for (int nt = 0; nt < 4; nt++) {
                float p = __expf(sv[i][nt] - m_new);
                sv[i][nt] = p;
                rs += p;
            }
            rs += __shfl_xor(rs, 1);
            rs += __shfl_xor(rs, 2);
            rs += __shfl_xor(rs, 4);
            rs += __shfl_xor(rs, 8);
            l_run[i] = l_run[i] * scale + rs;
            m_run[i] = m_new;
            #pragma unroll
            for (int dt = 0; dt < 4; dt++) oacc[dt][i] *= scale;
        }

        // ---- P (bf16) to LDS in A-frag-readable layout ----
        #pragma unroll
        for (int i = 0; i < 4; i++)
            #pragma unroll
            for (int nt = 0; nt < 4; nt++)
                Ps[(w * 16 + lk * 4 + i) * AST + nt * 16 + lr] = f2b(sv[i][nt]);
        __syncthreads();

        // ---- PV: O[16 q-rows][64 d] += P @ V ----
        #pragma unroll
        for (int ks = 0; ks < 2; ks++) {
            short8 ap = *(const short8*)&Ps[(w * 16 + lr) * AST + lk * 8 + ks * 32];
            #pragma unroll
            for (int dt = 0; dt < 4; dt++) {
                short8 bv = *(const short8*)&Vt[(dt * 16 + lr) * AST + lk * 8 + ks * 32];
                oacc[dt] = __builtin_amdgcn_mfma_f32_16x16x32_bf16(ap, bv, oacc[dt], 0, 0, 0);
            }
        }
    }

    // ---- epilogue ----
    #pragma unroll
    for (int i = 0; i < 4; i++) {
        const float inv = 1.0f / l_run[i];
        u16* dst = O + (size_t)(b * TT + q0 + w * 16 + lk * 4 + i) * 768 + h * 64 + lr;
        #pragma unroll
        for (int dt = 0; dt < 4; dt++)
            dst[dt * 16] = f2b(oacc[dt][i] * inv);
    }
}

// ---------------------------------------------------------------------------
// Host-side launch
// ---------------------------------------------------------------------------
extern "C" void kernel_launch(void* const* d_in, const int* in_sizes, int n_in,
                              void* d_out, int out_size, void* d_ws, size_t ws_size,
                              hipStream_t stream)
{
    (void)in_sizes; (void)n_in; (void)out_size; (void)ws_size;

    const int*   idx     = (const int*)  d_in[0];
    const float* tok_emb = (const float*)d_in[1];
    const float* pos_emb = (const float*)d_in[2];
    const float* ln1_w   = (const float*)d_in[3];
    const float* ln1_b   = (const float*)d_in[4];
    const float* wq      = (const float*)d_in[5];
    const float* wk      = (const float*)d_in[6];
    const float* wv      = (const float*)d_in[7];
    const float* wo      = (const float*)d_in[8];
    const float* bo      = (const float*)d_in[9];
    const float* ln2_w   = (const float*)d_in[10];
    const float* ln2_b   = (const float*)d_in[11];
    const float* w1      = (const float*)d_in[12];
    const float* b1      = (const float*)d_in[13];
    const float* w2      = (const float*)d_in[14];
    const float* b2      = (const float*)d_in[15];
    const float* lnf_w   = (const float*)d_in[16];
    const float* lnf_b   = (const float*)d_in[17];
    const float* head_w  = (const float*)d_in[18];
    const float* head_b  = (const float*)d_in[19];
    float* out = (float*)d_out;

    // workspace carve: ~112 MB
    const size_t S = (size_t)BT * EE;                 // 3,145,728
    float* x   = (float*)d_ws;                        // f32 [BT,768]
    u16*  qkv  = (u16*)(x + S);                       // bf16 [BT,2304]
    u16*  hb   = qkv + (size_t)BT * 2304;             // bf16 [BT,768]
    u16*  ffh  = hb + S;                              // bf16 [BT,3072]
    u16*  wt   = ffh + (size_t)BT * 3072;             // bf16 weights, reused per layer

    embed_kernel<<<BT * EE / 256, 256, 0, stream>>>(idx, tok_emb, pos_emb, x);

    for (int l = 0; l < L_LAYERS; l++) {
        const size_t oE  = (size_t)l * EE;
        const size_t oEE = (size_t)l * EE * EE;
        const size_t oEF = (size_t)l * EE * 4 * EE;

        // weight prep: all 6 matrices of this layer in one dispatch
        transpose_layer<<<6912, 256, 0, stream>>>(
            wq + oEE, wk + oEE, wv + oEE, wo + oEE, w1 + oEF, w2 + oEF, wt);

        // h = LN1(x)
        ln_kernel<<<BT, 256, 0, stream>>>(x, ln1_w + oE, ln1_b + oE, hb);
        // qkv = h @ [Wq|Wk|Wv]   (bf16 out)
        gemm_bf16<0, 0, 1, 4><<<dim3(BT / 128, 2304 / 128), 256, 0, stream>>>(
            hb, wt, nullptr, nullptr, qkv, BT, 2304, 768);
        // h = attention(qkv)  — MFMA flash
        attn_mfma<<<dim3(TT / 64, HH, BB), 256, 0, stream>>>(qkv, hb);
        // x = x + h @ Wo + bo   (TM=64: 384 blocks)
        gemm_bf16<0, 1, 0, 2><<<dim3(BT / 64, 768 / 128), 256, 0, stream>>>(
            hb, wt + (size_t)3 * 768 * 768, bo + oE, x, x, BT, 768, 768);
        // h = LN2(x)
        ln_kernel<<<BT, 256, 0, stream>>>(x, ln2_w + oE, ln2_b + oE, hb);
        // ffh = relu(h @ W1 + b1)  (bf16 out)
        gemm_bf16<1, 0, 1, 4><<<dim3(BT / 128, 3072 / 128), 256, 0, stream>>>(
            hb, wt + (size_t)4 * 768 * 768, b1 + (size_t)l * 4 * EE, nullptr, ffh, BT, 3072, 768);
        // x = x + ffh @ W2 + b2   (TM=64: 384 blocks)
        gemm_bf16<0, 1, 0, 2><<<dim3(BT / 64, 768 / 128), 256, 0, stream>>>(
            ffh, wt + (size_t)4 * 768 * 768 + (size_t)3072 * 768, b2 + oE, x, x, BT, 768, 3072);
    }

    // final LN + head
    ln_kernel<<<BT, 256, 0, stream>>>(x, lnf_w, lnf_b, hb);
    transpose_cvt<<<dim3(VV / 32, EE / 32), 256, 0, stream>>>(head_w, wt, EE, VV);
    gemm_bf16<0, 0, 0, 4><<<dim3(BT / 128, VV / 128), 256, 0, stream>>>(
        hb, wt, head_b, nullptr, out, BT, VV, 768);
}